// Round 3
// baseline (106.100 us; speedup 1.0000x reference)
//
#include <hip/hip_runtime.h>

// Problem constants (from reference setup_inputs)
#define BB 64
#define NN 128
#define DD 128
#define AA 1000
#define KPAD 1024
#define BK 64
#define NEG_INF (-9.0e15f)

typedef __attribute__((ext_vector_type(8))) short short8;   // 8 bf16 MFMA frag
typedef __attribute__((ext_vector_type(4))) float floatx4;  // MFMA C/D frag
typedef __attribute__((ext_vector_type(4))) unsigned int uintx4;
typedef __attribute__((ext_vector_type(2))) unsigned int uintx2;

__device__ __forceinline__ float bflo(unsigned int u) { return __uint_as_float(u << 16); }
__device__ __forceinline__ float bfhi(unsigned int u) { return __uint_as_float(u & 0xffff0000u); }
// truncating fp32->bf16 pack (cheap; ~2^-9 rel bias, fine vs threshold)
__device__ __forceinline__ unsigned int packbf(float f0, float f1) {
  return (__float_as_uint(f0) >> 16) | (__float_as_uint(f1) & 0xffff0000u);
}
// round-to-nearest-even fp32->bf16
__device__ __forceinline__ unsigned short bf_rne(float f) {
  unsigned int u = __float_as_uint(f);
  return (unsigned short)((u + 0x7fffu + ((u >> 16) & 1u)) >> 16);
}
__device__ __forceinline__ unsigned int packbf_rne(float f0, float f1) {
  return (unsigned int)bf_rne(f0) | ((unsigned int)bf_rne(f1) << 16);
}
__device__ __forceinline__ short8 u2s(uintx4 v) {
  union { uintx4 u; short8 s; } x; x.u = v; return x.s;
}

// ---------------------------------------------------------------------------
// Prep (96 blocks x 256): blocks 0..63 -> HTg[b][d][i] = bf16(h[b]^T);
// blocks 64..95 -> ET[c][k] = bf16(emb[k][c]) via coalesced rows + LDS
// transpose, k zero-padded to 1024. (Hg dropped: fused converts h in its
// latency-rich prologue.)
// ---------------------------------------------------------------------------
__global__ __launch_bounds__(256) void prep_kernel(
    const float* __restrict__ hidden, const float* __restrict__ emb,
    unsigned short* __restrict__ ET, unsigned short* __restrict__ HTg)
{
  __shared__ float hsf[NN * 129];
  const int t = threadIdx.x;
  const int bid = blockIdx.x;
  if (bid < BB) {
    const float* hb = hidden + (size_t)bid * NN * DD;
    #pragma unroll
    for (int u = 0; u < 16; ++u) {
      int e = u * 1024 + t * 4;
      float4 v = *reinterpret_cast<const float4*>(hb + e);
      int r = e >> 7, c = e & 127;
      float* d = &hsf[r * 129 + c];
      d[0] = v.x; d[1] = v.y; d[2] = v.z; d[3] = v.w;
    }
    __syncthreads();
    unsigned short* ht16 = HTg + (size_t)bid * NN * DD;
    #pragma unroll
    for (int u = 0; u < 8; ++u) {  // transpose via LDS columns
      int e = u * 2048 + t * 8;
      int dI = e >> 7, il = e & 127;
      float x[8];
      #pragma unroll
      for (int j = 0; j < 8; ++j) x[j] = hsf[(il + j) * 129 + dI];
      uintx4 o;
      o.x = packbf_rne(x[0], x[1]); o.y = packbf_rne(x[2], x[3]);
      o.z = packbf_rne(x[4], x[5]); o.w = packbf_rne(x[6], x[7]);
      *reinterpret_cast<uintx4*>(ht16 + e) = o;
    }
  } else {
    // ET transpose: 32 blocks, 32 k-rows each, coalesced emb reads.
    const int k0 = (bid - BB) * 32;
    #pragma unroll
    for (int u = 0; u < 4; ++u) {
      int e = u * 1024 + t * 4;
      int r = e >> 7, c = e & 127;
      float4 z = {0.f, 0.f, 0.f, 0.f};
      float4 v = (k0 + r < AA)
          ? *reinterpret_cast<const float4*>(emb + (size_t)(k0 + r) * DD + c) : z;
      float* d = &hsf[r * 129 + c];
      d[0] = v.x; d[1] = v.y; d[2] = v.z; d[3] = v.w;
    }
    __syncthreads();
    int c = t >> 1, j0 = (t & 1) * 16;
    float x[16];
    #pragma unroll
    for (int j = 0; j < 16; ++j) x[j] = hsf[(j0 + j) * 129 + c];
    uintx4 o0, o1;
    o0.x = packbf_rne(x[0], x[1]);  o0.y = packbf_rne(x[2], x[3]);
    o0.z = packbf_rne(x[4], x[5]);  o0.w = packbf_rne(x[6], x[7]);
    o1.x = packbf_rne(x[8], x[9]);  o1.y = packbf_rne(x[10], x[11]);
    o1.z = packbf_rne(x[12], x[13]); o1.w = packbf_rne(x[14], x[15]);
    unsigned short* dst = ET + (size_t)c * KPAD + k0 + j0;
    *reinterpret_cast<uintx4*>(dst) = o0;
    *reinterpret_cast<uintx4*>(dst + 8) = o1;
  }
}

// ---------------------------------------------------------------------------
// Fused kernel, grid = 256 = exactly 1 block/CU (LDS 94208 B), zero tail.
// Each block: one 32-row attr-GEMM tile (16 K-tiles = 16 barrier slots)
// WOVEN with two 16-row attn tiles of one batch b (14 attn phases mapped
// into the 16 slots). Every HBM-fetch latency window is filled with attn
// VALU/LDS/MFMA work; every attn LDS latency is filled with attr MFMA.
// Hs / hvq (QK B-frags) / pvb (PV B-frags) are shared by both attn tiles.
// ---------------------------------------------------------------------------
struct MergedSmem {
  // attn side
  __align__(16) unsigned short Hs[NN * 128];        // 32768 B bf16 h (swizzled)
  union {
    __align__(16) unsigned short As[2 * 16 * 256];  // 16384 B (QK, one k-pair)
    struct {
      __align__(16) float Sa[16 * 129];             // 8256 B (post-QK)
      __align__(16) unsigned short W[16 * 128];     // 4096 B (softmax out)
    } sw;
  } u2;
  __align__(16) float saf[4 * 256];                 // 4096 B scale table
  // attr side
  __align__(16) unsigned short ETs[2][DD * BK];     // 32768 B
  __align__(16) unsigned short As2[2][32 * BK];     // 8192 B
};  // 94208 B -> 1 block/CU

__global__ __launch_bounds__(256, 1) void fused_kernel(
    const float* __restrict__ hidden, const int* __restrict__ adj,
    const float* __restrict__ amat, const float* __restrict__ Aattr,
    const unsigned short* __restrict__ ET, const unsigned short* __restrict__ HTg,
    float* __restrict__ out0, float* __restrict__ out1)
{
  __shared__ MergedSmem s;
  const int t = threadIdx.x;
  const int L = t & 63, w = t >> 6;     // wave w = j-quarter / d-quarter / n-quarter
  const int lr = L & 15, lq = L >> 4;   // MFMA lane coords
  // XCD-chunked swizzle (256 % 8 == 0 -> bijective): XCD x gets wids
  // [32x,32x+32) -> batches [8x,8x+8) (L2-resident hidden/HTg/adj) and a
  // contiguous 4 MB Aattr chunk.
  const int bid = blockIdx.x;
  const int wid = (bid & 7) * 32 + (bid >> 3);
  const int b = wid >> 2;
  const int i0A = (wid & 3) * 32;       // attn tile A rows
  const int i0B = i0A + 16;             // attn tile B rows
  const int r0 = wid * 32;              // attr output rows

  // ---------------- attr pipeline state ----------------
  const int ar = t >> 3, ak = (t & 7) * 8;   // A: 8 threads/row, 8 floats each
  const int ec = t >> 1, ej0 = (t & 1) * 4;  // ET: 2 threads/row, 4x16B each
  const float* arow = Aattr + (size_t)(r0 + ar) * AA;
  const unsigned short* erow = ET + (size_t)ec * KPAD;
  float4 pa0[2], pa1[2];
  uintx4 pe[2][4];
  floatx4 acc2[2][2];
  #pragma unroll
  for (int mt = 0; mt < 2; ++mt)
    #pragma unroll
    for (int nt = 0; nt < 2; ++nt) acc2[mt][nt] = floatx4{0.f, 0.f, 0.f, 0.f};

#define AFETCH(SP, IT) do {                                                  \
    int kb = (IT) * BK; int k4 = kb + ak;                                    \
    float4 z = {0.f, 0.f, 0.f, 0.f};                                        \
    pa0[SP] = (k4 < AA) ? *reinterpret_cast<const float4*>(arow + k4) : z;   \
    pa1[SP] = (k4 + 4 < AA) ? *reinterpret_cast<const float4*>(arow + k4 + 4) : z; \
    _Pragma("unroll")                                                        \
    for (int q = 0; q < 4; ++q)                                              \
      pe[SP][q] = *reinterpret_cast<const uintx4*>(erow + kb + (ej0 + q) * 8); \
  } while (0)

#define ASTAGE(SP) do {                                                      \
    uintx4 o;                                                                \
    o.x = packbf(pa0[SP].x, pa0[SP].y); o.y = packbf(pa0[SP].z, pa0[SP].w);  \
    o.z = packbf(pa1[SP].x, pa1[SP].y); o.w = packbf(pa1[SP].z, pa1[SP].w);  \
    int ac = t & 7;                                                          \
    *reinterpret_cast<uintx4*>(&s.As2[SP][ar * BK + ((ac ^ (ar & 7)) << 3)]) = o; \
    _Pragma("unroll")                                                        \
    for (int q = 0; q < 4; ++q)                                              \
      *reinterpret_cast<uintx4*>(&s.ETs[SP][ec * BK + (((ej0 + q) ^ (ec & 7)) << 3)]) = pe[SP][q]; \
  } while (0)

#define ACOMPUTE(SP) do {                                                    \
    _Pragma("unroll")                                                        \
    for (int ks = 0; ks < 2; ++ks) {                                         \
      int c = lq + 4 * ks;                                                   \
      short8 af[2], bfv[2];                                                  \
      _Pragma("unroll")                                                      \
      for (int mt = 0; mt < 2; ++mt) {                                       \
        int row = mt * 16 + lr;                                              \
        af[mt] = *reinterpret_cast<const short8*>(                           \
            &s.As2[SP][row * BK + ((c ^ (row & 7)) << 3)]);                  \
      }                                                                      \
      _Pragma("unroll")                                                      \
      for (int nt = 0; nt < 2; ++nt) {                                       \
        int n = w * 32 + nt * 16 + lr;                                       \
        bfv[nt] = *reinterpret_cast<const short8*>(                          \
            &s.ETs[SP][n * BK + ((c ^ (n & 7)) << 3)]);                      \
      }                                                                      \
      _Pragma("unroll")                                                      \
      for (int mt = 0; mt < 2; ++mt)                                         \
        _Pragma("unroll")                                                    \
        for (int nt = 0; nt < 2; ++nt)                                       \
          acc2[mt][nt] = __builtin_amdgcn_mfma_f32_16x16x32_bf16(            \
              af[mt], bfv[nt], acc2[mt][nt], 0, 0, 0);                       \
    }                                                                        \
  } while (0)

  // ---------------- attn state ----------------
  floatx4 acc[4][2];
  uintx4 hvq[2][4];
  short8 pvb[2][4];

#define ZACC do {                                                            \
    _Pragma("unroll")                                                        \
    for (int k = 0; k < 4; ++k)                                              \
      _Pragma("unroll")                                                      \
      for (int nt = 0; nt < 2; ++nt) acc[k][nt] = floatx4{0.f, 0.f, 0.f, 0.f}; \
  } while (0)

#define HVQHOIST do {                                                        \
    _Pragma("unroll")                                                        \
    for (int nt = 0; nt < 2; ++nt)                                           \
      _Pragma("unroll")                                                      \
      for (int q = 0; q < 4; ++q) {                                          \
        int jrow = w * 32 + nt * 16 + lr;                                    \
        hvq[nt][q] = *reinterpret_cast<const uintx4*>(                       \
            &s.Hs[jrow * 128 + (((lq + 4 * q) ^ (jrow & 15)) << 3)]);        \
      }                                                                      \
  } while (0)

  // build As[kk][ii][d'] for edge-type pair KP (d'<128: h*0.6a ; >=128: |h|*0.4a)
#define ASBUILD(I0, KP) do {                                                 \
    _Pragma("unroll")                                                        \
    for (int u = 0; u < 4; ++u) {                                            \
      int id = u * 256 + t;                                                  \
      int kk = id >> 9, ii = (id >> 5) & 15, c = id & 31;                    \
      int srow = (I0) + ii;                                                  \
      int dchunk = c & 15;                                                   \
      uintx4 hv = *reinterpret_cast<const uintx4*>(                          \
          &s.Hs[srow * 128 + ((dchunk ^ (srow & 15)) << 3)]);                \
      if (c & 16) {                                                          \
        hv.x &= 0x7fff7fffu; hv.y &= 0x7fff7fffu;                            \
        hv.z &= 0x7fff7fffu; hv.w &= 0x7fff7fffu;                            \
      }                                                                      \
      const float* sf = &s.saf[((KP) * 2 + kk) * 256 + c * 8];               \
      uintx4 o;                                                              \
      o.x = packbf(bflo(hv.x) * sf[0], bfhi(hv.x) * sf[1]);                  \
      o.y = packbf(bflo(hv.y) * sf[2], bfhi(hv.y) * sf[3]);                  \
      o.z = packbf(bflo(hv.z) * sf[4], bfhi(hv.z) * sf[5]);                  \
      o.w = packbf(bflo(hv.w) * sf[6], bfhi(hv.w) * sf[7]);                  \
      *reinterpret_cast<uintx4*>(&s.u2.As[kk * 4096 + ii * 256 + ((c ^ ii) << 3)]) = o; \
    }                                                                        \
  } while (0)

#define QKPASS(KP) do {                                                      \
    _Pragma("unroll")                                                        \
    for (int kt2 = 0; kt2 < 8; ++kt2) {                                      \
      int ca = lq + 4 * kt2;                                                 \
      short8 afr[2];                                                         \
      _Pragma("unroll")                                                      \
      for (int kk = 0; kk < 2; ++kk)                                         \
        afr[kk] = *reinterpret_cast<const short8*>(                          \
            &s.u2.As[kk * 4096 + lr * 256 + ((ca ^ lr) << 3)]);              \
      _Pragma("unroll")                                                      \
      for (int nt = 0; nt < 2; ++nt) {                                       \
        uintx4 hv = hvq[nt][kt2 & 3];                                        \
        if (kt2 >= 4) {                                                      \
          hv.x &= 0x7fff7fffu; hv.y &= 0x7fff7fffu;                          \
          hv.z &= 0x7fff7fffu; hv.w &= 0x7fff7fffu;                          \
        }                                                                    \
        short8 bfr = u2s(hv);                                                \
        _Pragma("unroll")                                                    \
        for (int kk = 0; kk < 2; ++kk)                                       \
          acc[(KP) * 2 + kk][nt] = __builtin_amdgcn_mfma_f32_16x16x32_bf16(  \
              afr[kk], bfr, acc[(KP) * 2 + kk][nt], 0, 0, 0);                \
      }                                                                      \
    }                                                                        \
  } while (0)

  // in-register adj selection; C/D: col=lane&15, row=(lane>>4)*4+reg
#define SELPH(ADJV) do {                                                     \
    _Pragma("unroll")                                                        \
    for (int nt = 0; nt < 2; ++nt)                                           \
      _Pragma("unroll")                                                      \
      for (int r = 0; r < 4; ++r) {                                          \
        int ii = lq * 4 + r;                                                 \
        int j = w * 32 + nt * 16 + lr;                                       \
        int ad = ADJV[nt * 4 + r];                                           \
        float al = NEG_INF;                                                  \
        al = (ad == 1) ? acc[0][nt][r] : al;                                 \
        al = (ad == 2) ? acc[1][nt][r] : al;                                 \
        al = (ad == 3) ? acc[2][nt][r] : al;                                 \
        al = (ad == 4) ? acc[3][nt][r] : al;                                 \
        s.u2.sw.Sa[ii * 129 + j] = al;                                       \
      }                                                                      \
  } while (0)

  // softmax: one full row per wave (lane holds j=L and j=L+64)
#define SMPH do {                                                            \
    _Pragma("unroll")                                                        \
    for (int p = 0; p < 4; ++p) {                                            \
      int ii = w * 4 + p;                                                    \
      float a1 = s.u2.sw.Sa[ii * 129 + L];                                   \
      float a2 = s.u2.sw.Sa[ii * 129 + 64 + L];                              \
      float m = fmaxf(a1, a2);                                               \
      _Pragma("unroll")                                                      \
      for (int off = 32; off > 0; off >>= 1) m = fmaxf(m, __shfl_xor(m, off, 64)); \
      float e1 = __expf(fmaxf(a1 - m, -80.f));                               \
      float e2 = __expf(fmaxf(a2 - m, -80.f));                               \
      float ss = e1 + e2;                                                    \
      _Pragma("unroll")                                                      \
      for (int off = 32; off > 0; off >>= 1) ss += __shfl_xor(ss, off, 64);  \
      float inv = 1.f / ss;                                                  \
      int j2 = L + 64;                                                       \
      s.u2.sw.W[ii * 128 + (((L >> 3) ^ ii) << 3) + (L & 7)] = bf_rne(e1 * inv); \
      s.u2.sw.W[ii * 128 + (((j2 >> 3) ^ ii) << 3) + (j2 & 7)] = bf_rne(e2 * inv); \
    }                                                                        \
  } while (0)

#define PVPH(I0) do {                                                        \
    floatx4 oacc0 = floatx4{0.f, 0.f, 0.f, 0.f};                             \
    floatx4 oacc1 = floatx4{0.f, 0.f, 0.f, 0.f};                             \
    _Pragma("unroll")                                                        \
    for (int kt2 = 0; kt2 < 4; ++kt2) {                                      \
      int c = lq + 4 * kt2;                                                  \
      short8 wf = *reinterpret_cast<const short8*>(                          \
          &s.u2.sw.W[lr * 128 + ((c ^ lr) << 3)]);                           \
      oacc0 = __builtin_amdgcn_mfma_f32_16x16x32_bf16(wf, pvb[0][kt2], oacc0, 0, 0, 0); \
      oacc1 = __builtin_amdgcn_mfma_f32_16x16x32_bf16(wf, pvb[1][kt2], oacc1, 0, 0, 0); \
    }                                                                        \
    float* ob = out0 + ((size_t)b * NN + (I0)) * DD;                         \
    _Pragma("unroll")                                                        \
    for (int r = 0; r < 4; ++r) {                                            \
      ob[(lq * 4 + r) * DD + w * 32 + lr] = oacc0[r];                        \
      ob[(lq * 4 + r) * DD + w * 32 + 16 + lr] = oacc1[r];                   \
    }                                                                        \
  } while (0)

  // slot KT: barrier; issue fetch KT+2; attr MFMA on buffer KT&1; attn phase;
  // stage buffer (KT+1)&1 (its fetch was issued at slot KT-1 -> latency hidden
  // under this slot's compute).
#define SLOT(KT, ...) do {                                                   \
    __syncthreads();                                                         \
    if ((KT) < 14) { AFETCH((KT) & 1, (KT) + 2); }                           \
    ACOMPUTE((KT) & 1);                                                      \
    __VA_ARGS__                                                              \
    if ((KT) < 15) { ASTAGE(((KT) + 1) & 1); }                               \
  } while (0)

  // ---------------- prologue: issue every long-latency load ----------------
  AFETCH(0, 0);
  AFETCH(1, 1);
  // adj for both tiles (registers)
  const int* adjb = adj + (size_t)b * NN * NN;
  int adjvA[8], adjvB[8];
  #pragma unroll
  for (int nt = 0; nt < 2; ++nt)
    #pragma unroll
    for (int r = 0; r < 4; ++r) {
      int col = w * 32 + nt * 16 + lr;
      adjvA[nt * 4 + r] = adjb[(i0A + lq * 4 + r) * NN + col];
      adjvB[nt * 4 + r] = adjb[(i0B + lq * 4 + r) * NN + col];
    }
  // PV B-frags from HTg (shared by both tiles: depend only on b, lane)
  {
    const unsigned short* ht = HTg + (size_t)b * NN * DD;
    #pragma unroll
    for (int nt = 0; nt < 2; ++nt)
      #pragma unroll
      for (int kt2 = 0; kt2 < 4; ++kt2) {
        int dI = w * 32 + nt * 16 + lr;
        pvb[nt][kt2] = *reinterpret_cast<const short8*>(ht + dI * 128 + kt2 * 32 + lq * 8);
      }
  }
  // stage Hs from fp32 hidden (convert in flight; swizzle c^(row&15))
  {
    const float* hb = hidden + (size_t)b * NN * DD;
    #pragma unroll
    for (int u = 0; u < 8; ++u) {
      int id = u * 256 + t;
      int r = id >> 4, c = id & 15;
      const float* src = hb + r * 128 + c * 8;
      float4 v0 = *reinterpret_cast<const float4*>(src);
      float4 v1 = *reinterpret_cast<const float4*>(src + 4);
      uintx4 o;
      o.x = packbf_rne(v0.x, v0.y); o.y = packbf_rne(v0.z, v0.w);
      o.z = packbf_rne(v1.x, v1.y); o.w = packbf_rne(v1.z, v1.w);
      *reinterpret_cast<uintx4*>(&s.Hs[r * 128 + ((c ^ (r & 15)) << 3)]) = o;
    }
  }
  // scale table: saf[k][d]=0.6*a[d][k], saf[k][128+d]=0.4*a[d][k]
  {
    float v1 = amat[t], v2 = amat[t + 256];
    int dI = t >> 2, k = t & 3;
    s.saf[k * 256 + dI] = 0.6f * v1;
    s.saf[k * 256 + 128 + dI] = 0.4f * v1;
    s.saf[k * 256 + 64 + dI] = 0.6f * v2;
    s.saf[k * 256 + 192 + dI] = 0.4f * v2;
  }
  ZACC;
  ASTAGE(0);  // waits only on AFETCH(0)'s vmcnt slice

  // ---------------- the 16 woven slots ----------------
  SLOT(0,  { HVQHOIST; ASBUILD(i0A, 0); });
  SLOT(1,  { QKPASS(0); });
  SLOT(2,  { ASBUILD(i0A, 1); });
  SLOT(3,  { QKPASS(1); });
  SLOT(4,  { SELPH(adjvA); });
  SLOT(5,  { SMPH; });
  SLOT(6,  { PVPH(i0A); ZACC; });
  SLOT(7,  { ASBUILD(i0B, 0); });
  SLOT(8,  { QKPASS(0); });
  SLOT(9,  { ASBUILD(i0B, 1); });
  SLOT(10, { QKPASS(1); });
  SLOT(11, { SELPH(adjvB); });
  SLOT(12, { SMPH; });
  SLOT(13, { PVPH(i0B); });
  SLOT(14, {});
  SLOT(15, {});

  // ---------------- attr epilogue ----------------
  float* ob = out1 + (size_t)r0 * DD;
  #pragma unroll
  for (int mt = 0; mt < 2; ++mt)
    #pragma unroll
    for (int nt = 0; nt < 2; ++nt)
      #pragma unroll
      for (int r = 0; r < 4; ++r)
        ob[(mt * 16 + lq * 4 + r) * DD + w * 32 + nt * 16 + lr] = acc2[mt][nt][r];

#undef AFETCH
#undef ASTAGE
#undef ACOMPUTE
#undef ZACC
#undef HVQHOIST
#undef ASBUILD
#undef QKPASS
#undef SELPH
#undef SMPH
#undef PVPH
#undef SLOT
}

extern "C" void kernel_launch(void* const* d_in, const int* in_sizes, int n_in,
                              void* d_out, int out_size, void* d_ws, size_t ws_size,
                              hipStream_t stream) {
  const float* hidden = (const float*)d_in[0];  // [64,128,128] fp32
  const int*   adj    = (const int*)d_in[1];    // [64,128,128] int32
  const float* amat   = (const float*)d_in[2];  // [128,4] fp32
  const float* Aattr  = (const float*)d_in[3];  // [64,128,1000] fp32
  const float* emb    = (const float*)d_in[4];  // [1000,128] fp32

  float* out0 = (float*)d_out;                  // output    [64,128,128] fp32
  float* out1 = out0 + (size_t)BB * NN * DD;    // attr_sess [64,128,128] fp32

  // d_ws layout (rebuilt every call): bf16 operand copies
  unsigned short* ET  = (unsigned short*)d_ws;      // [128][1024]
  unsigned short* HTg = ET + (size_t)DD * KPAD;     // [64][128][128] h^T

  prep_kernel<<<BB + 32, 256, 0, stream>>>(hidden, emb, ET, HTg);
  fused_kernel<<<256, 256, 0, stream>>>(hidden, adj, amat, Aattr, ET, HTg,
                                        out0, out1);
}